// Round 10
// baseline (156.029 us; speedup 1.0000x reference)
//
#include <hip/hip_runtime.h>
#include <hip/hip_bf16.h>
#include <math.h>

#define NN 4096
#define DD 128

typedef __attribute__((ext_vector_type(8))) short bf16x8;
typedef __attribute__((ext_vector_type(4))) float f32x4;
#define AS3 __attribute__((address_space(3)))

// ws layout (doubles): gemm-loss slots ws[k*8], k=0..15; ws[128]=bqc1,
// ws[129]=bqc2, ws[130]=fdc.

__device__ __forceinline__ void gload_lds16(const float* g, float* l) {
    __builtin_amdgcn_global_load_lds((const __attribute__((address_space(1))) char*)g,
                                     (AS3 char*)l, 16, 0, 0);
}

// ---- fused prep: convert F (f32 [d][i]) -> bf16 [i][d]  +  bqc partials ----
__global__ __launch_bounds__(256)
void convert_bqc_kernel(const float* __restrict__ FP, const float* __restrict__ FM,
                        const float* __restrict__ B,
                        __hip_bfloat16* __restrict__ FPt, __hip_bfloat16* __restrict__ FMt,
                        double* __restrict__ ws)
{
    const int y = blockIdx.y;
    const float* src = y ? FM : FP;
    __hip_bfloat16* dst = y ? FMt : FPt;
    const int t  = threadIdx.x;
    const int il = t & 127;
    const int dh = t >> 7;
    const int i  = blockIdx.x * 128 + il;
    float s = 0.f;
    #pragma unroll
    for (int it = 0; it < 8; ++it) {
        const int d0 = dh * 64 + it * 8;
        float a[8];
        #pragma unroll
        for (int j = 0; j < 8; ++j) {
            a[j] = src[(long)(d0 + j) * NN + i];
            const float b = B[(long)(d0 + j) * NN + i];
            const float d = a[j] - b;
            s += d * d;
        }
        union { __hip_bfloat162 h[4]; bf16x8 v; } p;
        #pragma unroll
        for (int j = 0; j < 4; ++j)
            p.h[j] = __float22bfloat162_rn(make_float2(a[2*j], a[2*j+1]));
        *(bf16x8*)&dst[(long)i * DD + d0] = p.v;
    }
    __shared__ float red[4];
    #pragma unroll
    for (int off = 32; off; off >>= 1) s += __shfl_down(s, off);
    if ((t & 63) == 0) red[t >> 6] = s;
    __syncthreads();
    if (t == 0)
        atomicAdd(&ws[128 + y], (double)(red[0] + red[1] + red[2] + red[3]));
}

// ---- streaming fused gemm-loss --------------------------------------------
// Wave-tile = 16 i x 256 j. S staged via 16 global_load_lds, EACH a fully
// contiguous 1KB burst (lane L reads base + L*16B of ONE row) -> linear LDS
// (rows padded to 1040B: epilogue ds_read_b32 is 2-way conflict = free).
// 256 blocks x 4 waves = 1024 waves x 12 tiles; G = w*12 + t:
// z=G>>12, i0=((G>>4)&255)*16, j0=(G&15)*256  (per-wave: j sweeps -> rows
// stream sequentially). One-tile prefetch: 16KB/wave in flight forever.
__global__ __launch_bounds__(256, 1)
void gemm_loss_stream(const float* __restrict__ SU, const float* __restrict__ SP,
                      const float* __restrict__ SM,
                      const __hip_bfloat16* __restrict__ FPt_,
                      const __hip_bfloat16* __restrict__ FMt_,
                      double* __restrict__ accum)
{
    __shared__ float sS[4][2][4160];   // [wave][buf][16 rows x 260 floats]
    const int t0   = threadIdx.x;
    const int lane = t0 & 63, wid = t0 >> 6;
    const int l15  = lane & 15, l4 = lane >> 4;
    const int w    = blockIdx.x * 4 + wid;          // 0..1023
    const short* FPt = (const short*)FPt_;
    const short* FMt = (const short*)FMt_;
    const int foff = l4 * 8;                        // k-offset within fragment

#define STAGE(G_, b_)                                                          \
    {                                                                          \
        const int z_  = (G_) >> 12;                                            \
        const int i0_ = (((G_) >> 4) & 255) << 4;                              \
        const int j0_ = ((G_) & 15) << 8;                                      \
        const float* S_ = (z_ == 0) ? SU : (z_ == 1) ? SP : SM;                \
        const float* sp_ = S_ + (long)i0_ * NN + j0_ + lane * 4;               \
        float* d_ = &sS[wid][b_][0];                                           \
        _Pragma("unroll")                                                      \
        for (int q_ = 0; q_ < 16; ++q_)                                        \
            gload_lds16(sp_ + (long)q_ * NN, d_ + q_ * 260);                   \
    }

#define DSR(dst, ar, OFF) asm volatile("ds_read_b32 %0, %1 offset:" #OFF       \
                                       : "=v"(dst) : "v"(ar))
#define DSROW16(svr, ar)                                                       \
    DSR(svr[0], ar, 0);    DSR(svr[1], ar, 64);   DSR(svr[2], ar, 128);        \
    DSR(svr[3], ar, 192);  DSR(svr[4], ar, 256);  DSR(svr[5], ar, 320);        \
    DSR(svr[6], ar, 384);  DSR(svr[7], ar, 448);  DSR(svr[8], ar, 512);        \
    DSR(svr[9], ar, 576);  DSR(svr[10], ar, 640); DSR(svr[11], ar, 704);       \
    DSR(svr[12], ar, 768); DSR(svr[13], ar, 832); DSR(svr[14], ar, 896);       \
    DSR(svr[15], ar, 960)

    float ls0 = 0.f, ls1 = 0.f, ls2 = 0.f, ls3 = 0.f;

    // prologue: S(tile 0)
    STAGE(w * 12, 0);

    #pragma unroll 1
    for (int t = 0; t < 12; ++t) {
        const int G  = w * 12 + t;
        const int z  = G >> 12;
        const int i0 = ((G >> 4) & 255) << 4;
        const int j0 = (G & 15) << 8;
        const short* Fi = (z == 2) ? FMt : FPt;     // i-side (A operand)
        const short* Fj = (z == 1) ? FPt : FMt;     // j-side (B operand)
        const float onep = (z == 0) ? 1.0f : 1.0f + 1e-8f;

        // i-side fragments (4 loads)
        bf16x8 ai[4];
        #pragma unroll
        for (int kb = 0; kb < 4; ++kb)
            ai[kb] = *(const bf16x8*)&Fi[(long)(i0 + l15) * DD + kb * 32 + foff];

        // j-side fragments pipelined one jg-group ahead; 64 MFMAs
        f32x4 acc[16];
        bf16x8 fja[4];
        #pragma unroll
        for (int kb = 0; kb < 4; ++kb)
            fja[kb] = *(const bf16x8*)&Fj[(long)(j0 + l15) * DD + kb * 32 + foff];
        #pragma unroll
        for (int jg = 0; jg < 16; ++jg) {
            bf16x8 fjn[4];
            const int jn = (jg < 15) ? jg + 1 : 15;
            #pragma unroll
            for (int kb = 0; kb < 4; ++kb)
                fjn[kb] = *(const bf16x8*)&Fj[(long)(j0 + jn * 16 + l15) * DD + kb * 32 + foff];
            f32x4 a = {0.f, 0.f, 0.f, 0.f};
            #pragma unroll
            for (int kb = 0; kb < 4; ++kb)
                a = __builtin_amdgcn_mfma_f32_16x16x32_bf16(ai[kb], fja[kb], a, 0, 0, 0);
            acc[jg] = a;
            #pragma unroll
            for (int kb = 0; kb < 4; ++kb) fja[kb] = fjn[kb];
        }

        // stage next tile into the other buffer (youngest in VMEM FIFO)
        __builtin_amdgcn_sched_barrier(0);
        STAGE((t < 11) ? G + 1 : G, (t + 1) & 1);
        __builtin_amdgcn_sched_barrier(0);
        // wait: S(t) + all F frags done; S(t+1) (16 newest) stays in flight
        asm volatile("s_waitcnt vmcnt(16)");
        __builtin_amdgcn_sched_barrier(0);

        // epilogue: 64 asm ds_reads (compiler-blind), one lgkm wait
        const unsigned lbase = (unsigned)(unsigned long long)
            (AS3 float*)&sS[wid][t & 1][l4 * (4 * 260) + l15];
        const unsigned a0 = lbase, a1 = lbase + 1040,
                       a2 = lbase + 2080, a3 = lbase + 3120;
        float sv[4][16];
        DSROW16(sv[0], a0);
        DSROW16(sv[1], a1);
        DSROW16(sv[2], a2);
        DSROW16(sv[3], a3);
        asm volatile("s_waitcnt lgkmcnt(0)");
        __builtin_amdgcn_sched_barrier(0);

        #pragma unroll
        for (int jg = 0; jg < 16; ++jg) {
            const float o0 = 0.5f * acc[jg][0];
            const float o1 = 0.5f * acc[jg][1];
            const float o2 = 0.5f * acc[jg][2];
            const float o3 = 0.5f * acc[jg][3];
            ls0 += fmaf(-sv[0][jg], o0, __logf(o0 + onep));
            ls1 += fmaf(-sv[1][jg], o1, __logf(o1 + onep));
            ls2 += fmaf(-sv[2][jg], o2, __logf(o2 + onep));
            ls3 += fmaf(-sv[3][jg], o3, __logf(o3 + onep));
        }
    }
#undef DSROW16
#undef DSR
#undef STAGE

    float v = (ls0 + ls1) + (ls2 + ls3);
    #pragma unroll
    for (int off = 32; off; off >>= 1) v += __shfl_down(v, off);
    if (lane == 0)
        atomicAdd(accum + ((w & 15) << 3), (double)v);
}

// ---------------- fallback path (round-2 kernel, used if ws too small) ------
__global__ __launch_bounds__(256, 2)
void gemm_loss_mfma(const float* __restrict__ S, const float* __restrict__ F1,
                    const float* __restrict__ F2, float eps, double* __restrict__ accum)
{
    __shared__ char lds[2][128 * 256];
    __shared__ float red[4];
    const int t  = threadIdx.x;
    const int i0 = blockIdx.y * 128;
    const int j0 = blockIdx.x * 128;
    {
        const int il   = t & 127;
        const int half = t >> 7;
        const float* c1 = F1 + i0 + il;
        const float* c2 = F2 + j0 + il;
        char* r1 = lds[0] + il * 256;
        char* r2 = lds[1] + il * 256;
        #pragma unroll
        for (int it = 0; it < 8; ++it) {
            const int q  = half * 8 + it;
            const int d0 = q * 8;
            float a[8], b[8];
            #pragma unroll
            for (int j = 0; j < 8; ++j) {
                a[j] = c1[(long)(d0 + j) * NN];
                b[j] = c2[(long)(d0 + j) * NN];
            }
            union { __hip_bfloat162 h[4]; bf16x8 v; } pa, pb;
            #pragma unroll
            for (int j = 0; j < 4; ++j) {
                pa.h[j] = __float22bfloat162_rn(make_float2(a[2*j], a[2*j+1]));
                pb.h[j] = __float22bfloat162_rn(make_float2(b[2*j], b[2*j+1]));
            }
            const int off = (q ^ (il & 15)) << 4;
            *(bf16x8*)(r1 + off) = pa.v;
            *(bf16x8*)(r2 + off) = pb.v;
        }
    }
    __syncthreads();
    const int lane = t & 63;
    const int wid  = t >> 6;
    const int wr   = wid >> 1, wc = wid & 1;
    const int l15  = lane & 15, l4 = lane >> 4;
    float sreg[4][4][4];
    #pragma unroll
    for (int am = 0; am < 4; ++am)
        #pragma unroll
        for (int r = 0; r < 4; ++r) {
            const long gi    = (long)(i0 + wr * 64 + am * 16 + l4 * 4 + r);
            const long basep = gi * NN + j0 + wc * 64 + l15;
            #pragma unroll
            for (int bn = 0; bn < 4; ++bn)
                sreg[am][bn][r] = S[basep + bn * 16];
        }
    f32x4 acc[4][4] = {};
    #pragma unroll
    for (int kb = 0; kb < 4; ++kb) {
        bf16x8 af[4], bgr[4];
        #pragma unroll
        for (int m = 0; m < 4; ++m) {
            const int ia = wr * 64 + m * 16 + l15;
            af[m] = *(const bf16x8*)(lds[0] + ia * 256 + (((kb * 4 + l4) ^ l15) << 4));
            const int jbq = wc * 64 + m * 16 + l15;
            bgr[m] = *(const bf16x8*)(lds[1] + jbq * 256 + (((kb * 4 + l4) ^ l15) << 4));
        }
        #pragma unroll
        for (int m = 0; m < 4; ++m)
            #pragma unroll
            for (int n = 0; n < 4; ++n)
                acc[m][n] = __builtin_amdgcn_mfma_f32_16x16x32_bf16(af[m], bgr[n], acc[m][n], 0, 0, 0);
    }
    float lsum = 0.f;
    #pragma unroll
    for (int m = 0; m < 4; ++m)
        #pragma unroll
        for (int n = 0; n < 4; ++n)
            #pragma unroll
            for (int r = 0; r < 4; ++r) {
                const float o = 0.5f * acc[m][n][r];
                lsum += fmaf(-sreg[m][n][r], o, __logf(1.0f + o + eps));
            }
    float v = lsum;
    #pragma unroll
    for (int off = 32; off; off >>= 1) v += __shfl_down(v, off);
    if ((t & 63) == 0) red[t >> 6] = v;
    __syncthreads();
    if (t == 0) {
        const float tot = red[0] + red[1] + red[2] + red[3];
        atomicAdd(accum, (double)tot);   // slot 0
    }
}

// ---------------- small kernels ----------------
__global__ __launch_bounds__(256)
void bqc_kernel(const float* __restrict__ FP, const float* __restrict__ FM,
                const float* __restrict__ B, double* __restrict__ ws)
{
    __shared__ float red1[4], red2[4];
    const int n4 = DD * NN / 4;
    float s1 = 0.f, s2 = 0.f;
    for (int i = blockIdx.x * blockDim.x + threadIdx.x; i < n4;
         i += gridDim.x * blockDim.x) {
        const float4 p = ((const float4*)FP)[i];
        const float4 m = ((const float4*)FM)[i];
        const float4 b = ((const float4*)B)[i];
        float d;
        d = p.x - b.x; s1 += d * d;  d = p.y - b.y; s1 += d * d;
        d = p.z - b.z; s1 += d * d;  d = p.w - b.w; s1 += d * d;
        d = m.x - b.x; s2 += d * d;  d = m.y - b.y; s2 += d * d;
        d = m.z - b.z; s2 += d * d;  d = m.w - b.w; s2 += d * d;
    }
    const int t = threadIdx.x;
    #pragma unroll
    for (int off = 32; off; off >>= 1) {
        s1 += __shfl_down(s1, off);
        s2 += __shfl_down(s2, off);
    }
    if ((t & 63) == 0) { red1[t >> 6] = s1; red2[t >> 6] = s2; }
    __syncthreads();
    if (t == 0) {
        atomicAdd(&ws[128], (double)(red1[0] + red1[1] + red1[2] + red1[3]));
        atomicAdd(&ws[129], (double)(red2[0] + red2[1] + red2[2] + red2[3]));
    }
}

__global__ __launch_bounds__(256)
void fdc_kernel(const float* __restrict__ FP, const float* __restrict__ FM,
                double* __restrict__ ws)
{
    __shared__ float red[4];
    const float* F = (blockIdx.x >= DD) ? FM : FP;
    const int row = blockIdx.x & (DD - 1);
    float s = 0.f;
    const float4* rowp = (const float4*)&F[(long)row * NN];
    for (int i = threadIdx.x; i < NN / 4; i += blockDim.x) {
        const float4 v = rowp[i];
        s += v.x + v.y + v.z + v.w;
    }
    const int t = threadIdx.x;
    #pragma unroll
    for (int off = 32; off; off >>= 1) s += __shfl_down(s, off);
    if ((t & 63) == 0) red[t >> 6] = s;
    __syncthreads();
    if (t == 0) {
        const double rs = (double)(red[0] + red[1] + red[2] + red[3]);
        atomicAdd(&ws[130], rs * rs);
    }
}

__global__ void finalize_kernel(const double* __restrict__ ws, float* __restrict__ out)
{
    if (threadIdx.x == 0 && blockIdx.x == 0) {
        double s = 0.0;
        #pragma unroll
        for (int k = 0; k < 16; ++k) s += ws[k * 8];
        out[0] = (float)(s + ws[130] + sqrt(ws[128]) + sqrt(ws[129]));
    }
}

extern "C" void kernel_launch(void* const* d_in, const int* in_sizes, int n_in,
                              void* d_out, int out_size, void* d_ws, size_t ws_size,
                              hipStream_t stream)
{
    const float* SU = (const float*)d_in[0];
    const float* SP = (const float*)d_in[1];
    const float* SM = (const float*)d_in[2];
    const float* FP = (const float*)d_in[3];
    const float* FM = (const float*)d_in[4];
    const float* B  = (const float*)d_in[5];
    float*  out = (float*)d_out;
    double* ws  = (double*)d_ws;

    hipMemsetAsync(d_ws, 0, 4096, stream);

    const size_t fb   = (size_t)NN * DD * sizeof(__hip_bfloat16);   // 1 MB
    const size_t need = 4096 + 2 * fb;

    if (ws_size >= need) {
        char* base = (char*)d_ws + 4096;
        __hip_bfloat16* FPt = (__hip_bfloat16*)(base);
        __hip_bfloat16* FMt = (__hip_bfloat16*)(base + fb);
        convert_bqc_kernel<<<dim3(NN / 128, 2), 256, 0, stream>>>(FP, FM, B, FPt, FMt, ws);
        gemm_loss_stream<<<256, 256, 0, stream>>>(SU, SP, SM, FPt, FMt, ws);
        fdc_kernel<<<256, 256, 0, stream>>>(FP, FM, ws);
    } else {
        dim3 grid(NN / 128, NN / 128);
        gemm_loss_mfma<<<grid, 256, 0, stream>>>(SU, FP, FM, 0.0f, ws);
        gemm_loss_mfma<<<grid, 256, 0, stream>>>(SP, FP, FP, 1e-8f, ws);
        gemm_loss_mfma<<<grid, 256, 0, stream>>>(SM, FM, FM, 1e-8f, ws);
        bqc_kernel<<<512, 256, 0, stream>>>(FP, FM, B, ws);
        fdc_kernel<<<256, 256, 0, stream>>>(FP, FM, ws);
    }
    finalize_kernel<<<1, 64, 0, stream>>>(ws, out);
}

// Round 11
// 104.502 us; speedup vs baseline: 1.4931x; 1.4931x over previous
//
#include <hip/hip_runtime.h>
#include <hip/hip_bf16.h>
#include <math.h>

#define NN 4096
#define DD 128

typedef __attribute__((ext_vector_type(8))) short bf16x8;
typedef __attribute__((ext_vector_type(4))) float f32x4;

// ws layout (doubles): gemm-loss slots ws[k*8], k=0..15; ws[128]=bqc1,
// ws[129]=bqc2, ws[130]=fdc.

// ---- fused prep: convert F (f32 [d][i]) -> bf16 [i][d]  +  bqc partials ----
__global__ __launch_bounds__(256)
void convert_bqc_kernel(const float* __restrict__ FP, const float* __restrict__ FM,
                        const float* __restrict__ B,
                        __hip_bfloat16* __restrict__ FPt, __hip_bfloat16* __restrict__ FMt,
                        double* __restrict__ ws)
{
    const int y = blockIdx.y;
    const float* src = y ? FM : FP;
    __hip_bfloat16* dst = y ? FMt : FPt;
    const int t  = threadIdx.x;
    const int il = t & 127;
    const int dh = t >> 7;
    const int i  = blockIdx.x * 128 + il;
    float s = 0.f;
    #pragma unroll
    for (int it = 0; it < 8; ++it) {
        const int d0 = dh * 64 + it * 8;
        float a[8];
        #pragma unroll
        for (int j = 0; j < 8; ++j) {
            a[j] = src[(long)(d0 + j) * NN + i];
            const float b = B[(long)(d0 + j) * NN + i];
            const float d = a[j] - b;
            s += d * d;
        }
        union { __hip_bfloat162 h[4]; bf16x8 v; } p;
        #pragma unroll
        for (int j = 0; j < 4; ++j)
            p.h[j] = __float22bfloat162_rn(make_float2(a[2*j], a[2*j+1]));
        *(bf16x8*)&dst[(long)i * DD + d0] = p.v;
    }
    __shared__ float red[4];
    #pragma unroll
    for (int off = 32; off; off >>= 1) s += __shfl_down(s, off);
    if ((t & 63) == 0) red[t >> 6] = s;
    __syncthreads();
    if (t == 0)
        atomicAdd(&ws[128 + y], (double)(red[0] + red[1] + red[2] + red[3]));
}

// ---- fused gemm-loss: F entirely in LDS, S is the ONLY VMEM stream --------
// Block = 256i x 256j tile, 512 threads (8 waves), 1 block/CU (128KB LDS).
// Stage Fi (256 rows [i][d] bf16, XOR-swizzled) + Fj once -> all fragments
// via ds_read_b128 (LDS pipe, not VMEM). F:S VMEM ratio = 0.5.
// Swapped MFMA (A=Fj, B=Fi) => acc = Omega^T: lane's 4 acc regs are 4
// consecutive j -> S loads are float4 (64B bursts, 8 instr / 8KB chunk).
// Wave = (wr = i-half, wc = j-quarter) -> 128i x 64j, 4 chunks of 32i.
__global__ __launch_bounds__(512, 2)
void gemm_loss_ldsf(const float* __restrict__ SU, const float* __restrict__ SP,
                    const float* __restrict__ SM,
                    const __hip_bfloat16* __restrict__ FPt_,
                    const __hip_bfloat16* __restrict__ FMt_,
                    double* __restrict__ accum)
{
    __shared__ char lds[131072];
    char* sFi = lds;
    char* sFj = lds + 65536;

    const int t    = threadIdx.x;
    const int lane = t & 63, wid = t >> 6;
    const int l15  = lane & 15, l4 = lane >> 4;
    const int z    = blockIdx.z;
    const int i0   = blockIdx.y * 256;
    const int j0   = blockIdx.x * 256;
    const short* FPt = (const short*)FPt_;
    const short* FMt = (const short*)FMt_;
    const float* S  = (z == 0) ? SU : (z == 1) ? SP : SM;
    const short* Fi = (z == 2) ? FMt : FPt;    // i-side
    const short* Fj = (z == 1) ? FPt : FMt;    // j-side
    const float onep = (z == 0) ? 1.0f : 1.0f + 1e-8f;

    // ---- stage both F tiles into LDS (the ONLY F VMEM traffic: 128KB) ----
    {
        const int il = t & 255;      // row
        const int h  = t >> 8;       // chunk half
        const int sw = il & 15;
        #pragma unroll
        for (int q8 = 0; q8 < 8; ++q8) {
            const int q = h * 8 + q8;
            const bf16x8 vi = *(const bf16x8*)&Fi[(long)(i0 + il) * DD + q * 8];
            const bf16x8 vj = *(const bf16x8*)&Fj[(long)(j0 + il) * DD + q * 8];
            *(bf16x8*)(sFi + il * 256 + ((q ^ sw) << 4)) = vi;
            *(bf16x8*)(sFj + il * 256 + ((q ^ sw) << 4)) = vj;
        }
    }
    __syncthreads();

    const int wr = wid >> 2;         // i-half (0..1)
    const int wc = wid & 3;          // j-quarter (0..3)

    // hoisted j-side fragments (A operand) for the wave's 64 j: 16 ds_read_b128
    bf16x8 bj[4][4];
    #pragma unroll
    for (int nj = 0; nj < 4; ++nj)
        #pragma unroll
        for (int kb = 0; kb < 4; ++kb) {
            const int row = wc * 64 + nj * 16 + l15;
            bj[nj][kb] = *(const bf16x8*)(sFj + row * 256 + (((kb * 4 + l4) ^ (row & 15)) << 4));
        }

    // per-lane S base: i = i0 + wr*128 + l15 (col of Omega^T), j block by l4
    const float* sp = S + (long)(i0 + wr * 128 + l15) * NN + j0 + wc * 64 + l4 * 4;

    float lsum = 0.f;
    f32x4 sv0[2][4], sv1[2][4], sv2[2][4], sv3[2][4];

    // prologue: S chunk 0
    #pragma unroll
    for (int mi = 0; mi < 2; ++mi)
        #pragma unroll
        for (int nj = 0; nj < 4; ++nj)
            sv0[mi][nj] = *(const f32x4*)(sp + (long)(mi * 16) * NN + nj * 16);

#define CHUNK(c, cur, nxt, DO_PRE)                                             \
    {                                                                          \
        if (DO_PRE) {                                                          \
            _Pragma("unroll")                                                  \
            for (int mi = 0; mi < 2; ++mi)                                     \
                _Pragma("unroll")                                              \
                for (int nj = 0; nj < 4; ++nj)                                 \
                    nxt[mi][nj] = *(const f32x4*)(sp + (long)((c + 1) * 32 + mi * 16) * NN + nj * 16); \
        }                                                                      \
        bf16x8 ai[2][4];                                                       \
        _Pragma("unroll")                                                      \
        for (int mi = 0; mi < 2; ++mi)                                         \
            _Pragma("unroll")                                                  \
            for (int kb = 0; kb < 4; ++kb) {                                   \
                const int row = wr * 128 + (c) * 32 + mi * 16 + l15;           \
                ai[mi][kb] = *(const bf16x8*)(sFi + row * 256 + (((kb * 4 + l4) ^ (row & 15)) << 4)); \
            }                                                                  \
        f32x4 acc[2][4] = {};                                                  \
        _Pragma("unroll")                                                      \
        for (int kb = 0; kb < 4; ++kb)                                         \
            _Pragma("unroll")                                                  \
            for (int mi = 0; mi < 2; ++mi)                                     \
                _Pragma("unroll")                                              \
                for (int nj = 0; nj < 4; ++nj)                                 \
                    acc[mi][nj] = __builtin_amdgcn_mfma_f32_16x16x32_bf16(bj[nj][kb], ai[mi][kb], acc[mi][nj], 0, 0, 0); \
        _Pragma("unroll")                                                      \
        for (int mi = 0; mi < 2; ++mi)                                         \
            _Pragma("unroll")                                                  \
            for (int nj = 0; nj < 4; ++nj)                                     \
                _Pragma("unroll")                                              \
                for (int r = 0; r < 4; ++r) {                                  \
                    const float o = 0.5f * acc[mi][nj][r];                     \
                    lsum += fmaf(-cur[mi][nj][r], o, __logf(o + onep));        \
                }                                                              \
    }

    CHUNK(0, sv0, sv1, 1);
    CHUNK(1, sv1, sv2, 1);
    CHUNK(2, sv2, sv3, 1);
    CHUNK(3, sv3, sv0, 0);
#undef CHUNK

    float v = lsum;
    #pragma unroll
    for (int off = 32; off; off >>= 1) v += __shfl_down(v, off);
    if (lane == 0)
        atomicAdd(accum + (((blockIdx.x + blockIdx.y) & 15) << 3), (double)v);
}

// ---------------- fallback path (round-2 kernel, used if ws too small) ------
__global__ __launch_bounds__(256, 2)
void gemm_loss_mfma(const float* __restrict__ S, const float* __restrict__ F1,
                    const float* __restrict__ F2, float eps, double* __restrict__ accum)
{
    __shared__ char lds[2][128 * 256];
    __shared__ float red[4];
    const int t  = threadIdx.x;
    const int i0 = blockIdx.y * 128;
    const int j0 = blockIdx.x * 128;
    {
        const int il   = t & 127;
        const int half = t >> 7;
        const float* c1 = F1 + i0 + il;
        const float* c2 = F2 + j0 + il;
        char* r1 = lds[0] + il * 256;
        char* r2 = lds[1] + il * 256;
        #pragma unroll
        for (int it = 0; it < 8; ++it) {
            const int q  = half * 8 + it;
            const int d0 = q * 8;
            float a[8], b[8];
            #pragma unroll
            for (int j = 0; j < 8; ++j) {
                a[j] = c1[(long)(d0 + j) * NN];
                b[j] = c2[(long)(d0 + j) * NN];
            }
            union { __hip_bfloat162 h[4]; bf16x8 v; } pa, pb;
            #pragma unroll
            for (int j = 0; j < 4; ++j) {
                pa.h[j] = __float22bfloat162_rn(make_float2(a[2*j], a[2*j+1]));
                pb.h[j] = __float22bfloat162_rn(make_float2(b[2*j], b[2*j+1]));
            }
            const int off = (q ^ (il & 15)) << 4;
            *(bf16x8*)(r1 + off) = pa.v;
            *(bf16x8*)(r2 + off) = pb.v;
        }
    }
    __syncthreads();
    const int lane = t & 63;
    const int wid  = t >> 6;
    const int wr   = wid >> 1, wc = wid & 1;
    const int l15  = lane & 15, l4 = lane >> 4;
    float sreg[4][4][4];
    #pragma unroll
    for (int am = 0; am < 4; ++am)
        #pragma unroll
        for (int r = 0; r < 4; ++r) {
            const long gi    = (long)(i0 + wr * 64 + am * 16 + l4 * 4 + r);
            const long basep = gi * NN + j0 + wc * 64 + l15;
            #pragma unroll
            for (int bn = 0; bn < 4; ++bn)
                sreg[am][bn][r] = S[basep + bn * 16];
        }
    f32x4 acc[4][4] = {};
    #pragma unroll
    for (int kb = 0; kb < 4; ++kb) {
        bf16x8 af[4], bgr[4];
        #pragma unroll
        for (int m = 0; m < 4; ++m) {
            const int ia = wr * 64 + m * 16 + l15;
            af[m] = *(const bf16x8*)(lds[0] + ia * 256 + (((kb * 4 + l4) ^ l15) << 4));
            const int jbq = wc * 64 + m * 16 + l15;
            bgr[m] = *(const bf16x8*)(lds[1] + jbq * 256 + (((kb * 4 + l4) ^ l15) << 4));
        }
        #pragma unroll
        for (int m = 0; m < 4; ++m)
            #pragma unroll
            for (int n = 0; n < 4; ++n)
                acc[m][n] = __builtin_amdgcn_mfma_f32_16x16x32_bf16(af[m], bgr[n], acc[m][n], 0, 0, 0);
    }
    float lsum = 0.f;
    #pragma unroll
    for (int m = 0; m < 4; ++m)
        #pragma unroll
        for (int n = 0; n < 4; ++n)
            #pragma unroll
            for (int r = 0; r < 4; ++r) {
                const float o = 0.5f * acc[m][n][r];
                lsum += fmaf(-sreg[m][n][r], o, __logf(1.0f + o + eps));
            }
    float v = lsum;
    #pragma unroll
    for (int off = 32; off; off >>= 1) v += __shfl_down(v, off);
    if ((t & 63) == 0) red[t >> 6] = v;
    __syncthreads();
    if (t == 0) {
        const float tot = red[0] + red[1] + red[2] + red[3];
        atomicAdd(accum, (double)tot);   // slot 0
    }
}

// ---------------- small kernels ----------------
__global__ __launch_bounds__(256)
void bqc_kernel(const float* __restrict__ FP, const float* __restrict__ FM,
                const float* __restrict__ B, double* __restrict__ ws)
{
    __shared__ float red1[4], red2[4];
    const int n4 = DD * NN / 4;
    float s1 = 0.f, s2 = 0.f;
    for (int i = blockIdx.x * blockDim.x + threadIdx.x; i < n4;
         i += gridDim.x * blockDim.x) {
        const float4 p = ((const float4*)FP)[i];
        const float4 m = ((const float4*)FM)[i];
        const float4 b = ((const float4*)B)[i];
        float d;
        d = p.x - b.x; s1 += d * d;  d = p.y - b.y; s1 += d * d;
        d = p.z - b.z; s1 += d * d;  d = p.w - b.w; s1 += d * d;
        d = m.x - b.x; s2 += d * d;  d = m.y - b.y; s2 += d * d;
        d = m.z - b.z; s2 += d * d;  d = m.w - b.w; s2 += d * d;
    }
    const int t = threadIdx.x;
    #pragma unroll
    for (int off = 32; off; off >>= 1) {
        s1 += __shfl_down(s1, off);
        s2 += __shfl_down(s2, off);
    }
    if ((t & 63) == 0) { red1[t >> 6] = s1; red2[t >> 6] = s2; }
    __syncthreads();
    if (t == 0) {
        atomicAdd(&ws[128], (double)(red1[0] + red1[1] + red1[2] + red1[3]));
        atomicAdd(&ws[129], (double)(red2[0] + red2[1] + red2[2] + red2[3]));
    }
}

__global__ __launch_bounds__(256)
void fdc_kernel(const float* __restrict__ FP, const float* __restrict__ FM,
                double* __restrict__ ws)
{
    __shared__ float red[4];
    const float* F = (blockIdx.x >= DD) ? FM : FP;
    const int row = blockIdx.x & (DD - 1);
    float s = 0.f;
    const float4* rowp = (const float4*)&F[(long)row * NN];
    for (int i = threadIdx.x; i < NN / 4; i += blockDim.x) {
        const float4 v = rowp[i];
        s += v.x + v.y + v.z + v.w;
    }
    const int t = threadIdx.x;
    #pragma unroll
    for (int off = 32; off; off >>= 1) s += __shfl_down(s, off);
    if ((t & 63) == 0) red[t >> 6] = s;
    __syncthreads();
    if (t == 0) {
        const double rs = (double)(red[0] + red[1] + red[2] + red[3]);
        atomicAdd(&ws[130], rs * rs);
    }
}

__global__ void finalize_kernel(const double* __restrict__ ws, float* __restrict__ out)
{
    if (threadIdx.x == 0 && blockIdx.x == 0) {
        double s = 0.0;
        #pragma unroll
        for (int k = 0; k < 16; ++k) s += ws[k * 8];
        out[0] = (float)(s + ws[130] + sqrt(ws[128]) + sqrt(ws[129]));
    }
}

extern "C" void kernel_launch(void* const* d_in, const int* in_sizes, int n_in,
                              void* d_out, int out_size, void* d_ws, size_t ws_size,
                              hipStream_t stream)
{
    const float* SU = (const float*)d_in[0];
    const float* SP = (const float*)d_in[1];
    const float* SM = (const float*)d_in[2];
    const float* FP = (const float*)d_in[3];
    const float* FM = (const float*)d_in[4];
    const float* B  = (const float*)d_in[5];
    float*  out = (float*)d_out;
    double* ws  = (double*)d_ws;

    hipMemsetAsync(d_ws, 0, 4096, stream);

    const size_t fb   = (size_t)NN * DD * sizeof(__hip_bfloat16);   // 1 MB
    const size_t need = 4096 + 2 * fb;

    if (ws_size >= need) {
        char* base = (char*)d_ws + 4096;
        __hip_bfloat16* FPt = (__hip_bfloat16*)(base);
        __hip_bfloat16* FMt = (__hip_bfloat16*)(base + fb);
        convert_bqc_kernel<<<dim3(NN / 128, 2), 256, 0, stream>>>(FP, FM, B, FPt, FMt, ws);
        gemm_loss_ldsf<<<dim3(16, 16, 3), 512, 0, stream>>>(SU, SP, SM, FPt, FMt, ws);
        fdc_kernel<<<256, 256, 0, stream>>>(FP, FM, ws);
    } else {
        dim3 grid(NN / 128, NN / 128);
        gemm_loss_mfma<<<grid, 256, 0, stream>>>(SU, FP, FM, 0.0f, ws);
        gemm_loss_mfma<<<grid, 256, 0, stream>>>(SP, FP, FP, 1e-8f, ws);
        gemm_loss_mfma<<<grid, 256, 0, stream>>>(SM, FM, FM, 1e-8f, ws);
        bqc_kernel<<<512, 256, 0, stream>>>(FP, FM, B, ws);
        fdc_kernel<<<256, 256, 0, stream>>>(FP, FM, ws);
    }
    finalize_kernel<<<1, 64, 0, stream>>>(ws, out);
}

// Round 13
// 97.860 us; speedup vs baseline: 1.5944x; 1.0679x over previous
//
#include <hip/hip_runtime.h>
#include <hip/hip_bf16.h>
#include <math.h>

#define NN 4096
#define DD 128

typedef __attribute__((ext_vector_type(8))) short bf16x8;
typedef __attribute__((ext_vector_type(4))) float f32x4;
#define AS3 __attribute__((address_space(3)))

// ws layout (doubles): gemm-loss slots ws[k*8], k=0..15; ws[128]=bqc1,
// ws[129]=bqc2, ws[130]=fdc.

__device__ __forceinline__ void gload_lds16(const float* g, float* l) {
    __builtin_amdgcn_global_load_lds((const __attribute__((address_space(1))) char*)g,
                                     (AS3 char*)l, 16, 0, 0);
}

// ---- fused prep: convert F (f32 [d][i]) -> bf16 [i][d]  +  bqc partials ----
__global__ __launch_bounds__(256)
void convert_bqc_kernel(const float* __restrict__ FP, const float* __restrict__ FM,
                        const float* __restrict__ B,
                        __hip_bfloat16* __restrict__ FPt, __hip_bfloat16* __restrict__ FMt,
                        double* __restrict__ ws)
{
    const int y = blockIdx.y;
    const float* src = y ? FM : FP;
    __hip_bfloat16* dst = y ? FMt : FPt;
    const int t  = threadIdx.x;
    const int il = t & 127;
    const int dh = t >> 7;
    const int i  = blockIdx.x * 128 + il;
    float s = 0.f;
    #pragma unroll
    for (int it = 0; it < 8; ++it) {
        const int d0 = dh * 64 + it * 8;
        float a[8];
        #pragma unroll
        for (int j = 0; j < 8; ++j) {
            a[j] = src[(long)(d0 + j) * NN + i];
            const float b = B[(long)(d0 + j) * NN + i];
            const float d = a[j] - b;
            s += d * d;
        }
        union { __hip_bfloat162 h[4]; bf16x8 v; } p;
        #pragma unroll
        for (int j = 0; j < 4; ++j)
            p.h[j] = __float22bfloat162_rn(make_float2(a[2*j], a[2*j+1]));
        *(bf16x8*)&dst[(long)i * DD + d0] = p.v;
    }
    __shared__ float red[4];
    #pragma unroll
    for (int off = 32; off; off >>= 1) s += __shfl_down(s, off);
    if ((t & 63) == 0) red[t >> 6] = s;
    __syncthreads();
    if (t == 0)
        atomicAdd(&ws[128 + y], (double)(red[0] + red[1] + red[2] + red[3]));
}

// ---- fused gemm-loss, address-diversity mapping (corrected coverage) ------
// 768 blocks x 4 waves = 3072 waves; wave = [z(3)][i-block(128)][j-window(8)]:
// z and i0 CONSTANT per wave (af hoisted); wave sweeps 16 consecutive j-tiles
// (32 j each -> 512 consecutive columns). 3072 x 16 = 49152 tiles = full
// 3 x 128 x 128 coverage. Concurrent waves differ in z (separate allocations
// -> independent channel phases), i-block, and j-window.
// Per tile: [bg(t+1): 8 loads] [S(t+1): 4 global_load_lds] [vmcnt(12): all
// older done, exactly those 12 in flight] [16 MFMA] [epilogue from LDS].
__global__ __launch_bounds__(256, 3)
void gemm_loss_sweep(const float* __restrict__ SU, const float* __restrict__ SP,
                     const float* __restrict__ SM,
                     const __hip_bfloat16* __restrict__ FPt_,
                     const __hip_bfloat16* __restrict__ FMt_,
                     double* __restrict__ accum)
{
    __shared__ float sS[4][2][1024];   // [wave][buf][32i x 32j]
    const int t0   = threadIdx.x;
    const int lane = t0 & 63, wid = t0 >> 6;
    const int l15  = lane & 15, l4 = lane >> 4;
    const int w    = blockIdx.x * 4 + wid;      // 0..3071
    const int z    = w >> 10;                   // constant per wave
    const int rem  = w & 1023;
    const int i0   = (rem >> 3) << 5;           // 128 i-blocks, constant/wave
    const int jw   = rem & 7;                   // j-window: tiles jw*16..+15
    const short* FPt = (const short*)FPt_;
    const short* FMt = (const short*)FMt_;
    const float* S  = (z == 0) ? SU : (z == 1) ? SP : SM;
    const short* Fa = (z == 2) ? FMt : FPt;     // i-side (A operand)
    const short* Fb = (z == 1) ? FPt : FMt;     // j-side (B operand)
    const float onep = (z == 0) ? 1.0f : 1.0f + 1e-8f;

    // hoisted i-side fragments (z, i0 fixed per wave)
    bf16x8 af[2][4];
    #pragma unroll
    for (int m = 0; m < 2; ++m)
        #pragma unroll
        for (int kb = 0; kb < 4; ++kb)
            af[m][kb] = *(const bf16x8*)&Fa[(long)(i0 + m * 16 + l15) * DD + kb * 32 + l4 * 8];

    float lsum = 0.f;
    bf16x8 bgA[2][4], bgB[2][4];

#define LOADBG(jt, dst)                                                        \
    {                                                                          \
        const int j0_ = (jt) << 5;                                             \
        _Pragma("unroll")                                                      \
        for (int n = 0; n < 2; ++n)                                            \
            _Pragma("unroll")                                                  \
            for (int kb = 0; kb < 4; ++kb)                                     \
                dst[n][kb] = *(const bf16x8*)&Fb[(long)(j0_ + n * 16 + l15) * DD + kb * 32 + l4 * 8]; \
    }

#define STAGE(jt, buf)                                                         \
    {                                                                          \
        const int j0_ = (jt) << 5;                                             \
        const float* src_ = S + (long)(i0 + (lane >> 3)) * NN + j0_ + (lane & 7) * 4; \
        float* d_ = &sS[wid][buf][0];                                          \
        _Pragma("unroll")                                                      \
        for (int q_ = 0; q_ < 4; ++q_)                                         \
            gload_lds16(src_ + (long)q_ * 8 * NN, d_ + q_ * 256);              \
    }

#define TILE_BODY(tt, cur, nxt)                                                \
    {                                                                          \
        const int tc = (tt);                                                   \
        const int tn = (tc < 15) ? tc + 1 : 15;                                \
        LOADBG(jw * 16 + tn, nxt);                                             \
        __builtin_amdgcn_sched_barrier(0);                                     \
        STAGE(jw * 16 + tn, (tc + 1) & 1);                                     \
        __builtin_amdgcn_sched_barrier(0);                                     \
        asm volatile("s_waitcnt vmcnt(12)");                                   \
        __builtin_amdgcn_sched_barrier(0);                                     \
        f32x4 acc[2][2] = {};                                                  \
        _Pragma("unroll")                                                      \
        for (int kb = 0; kb < 4; ++kb)                                         \
            _Pragma("unroll")                                                  \
            for (int m = 0; m < 2; ++m)                                        \
                _Pragma("unroll")                                              \
                for (int n = 0; n < 2; ++n)                                    \
                    acc[m][n] = __builtin_amdgcn_mfma_f32_16x16x32_bf16(af[m][kb], cur[n][kb], acc[m][n], 0, 0, 0); \
        const float* q = &sS[wid][tc & 1][0];                                  \
        _Pragma("unroll")                                                      \
        for (int m = 0; m < 2; ++m)                                            \
            _Pragma("unroll")                                                  \
            for (int n = 0; n < 2; ++n)                                        \
                _Pragma("unroll")                                              \
                for (int r = 0; r < 4; ++r) {                                  \
                    const float s = q[(m * 16 + l4 * 4 + r) * 32 + n * 16 + l15]; \
                    const float o = 0.5f * acc[m][n][r];                       \
                    lsum += fmaf(-s, o, __logf(o + onep));                     \
                }                                                              \
    }

    // prologue: bg(tile 0) + S(tile 0); af already issued (oldest in FIFO)
    LOADBG(jw * 16, bgA);
    STAGE(jw * 16, 0);

    #pragma unroll 1
    for (int t = 0; t < 16; t += 2) {
        TILE_BODY(t,     bgA, bgB);
        TILE_BODY(t + 1, bgB, bgA);
    }
#undef TILE_BODY
#undef STAGE
#undef LOADBG

    float v = lsum;
    #pragma unroll
    for (int off = 32; off; off >>= 1) v += __shfl_down(v, off);
    if (lane == 0)
        atomicAdd(accum + ((w & 15) << 3), (double)v);
}

// ---------------- fallback path (round-2 kernel, used if ws too small) ------
__global__ __launch_bounds__(256, 2)
void gemm_loss_mfma(const float* __restrict__ S, const float* __restrict__ F1,
                    const float* __restrict__ F2, float eps, double* __restrict__ accum)
{
    __shared__ char lds[2][128 * 256];
    __shared__ float red[4];
    const int t  = threadIdx.x;
    const int i0 = blockIdx.y * 128;
    const int j0 = blockIdx.x * 128;
    {
        const int il   = t & 127;
        const int half = t >> 7;
        const float* c1 = F1 + i0 + il;
        const float* c2 = F2 + j0 + il;
        char* r1 = lds[0] + il * 256;
        char* r2 = lds[1] + il * 256;
        #pragma unroll
        for (int it = 0; it < 8; ++it) {
            const int q  = half * 8 + it;
            const int d0 = q * 8;
            float a[8], b[8];
            #pragma unroll
            for (int j = 0; j < 8; ++j) {
                a[j] = c1[(long)(d0 + j) * NN];
                b[j] = c2[(long)(d0 + j) * NN];
            }
            union { __hip_bfloat162 h[4]; bf16x8 v; } pa, pb;
            #pragma unroll
            for (int j = 0; j < 4; ++j) {
                pa.h[j] = __float22bfloat162_rn(make_float2(a[2*j], a[2*j+1]));
                pb.h[j] = __float22bfloat162_rn(make_float2(b[2*j], b[2*j+1]));
            }
            const int off = (q ^ (il & 15)) << 4;
            *(bf16x8*)(r1 + off) = pa.v;
            *(bf16x8*)(r2 + off) = pb.v;
        }
    }
    __syncthreads();
    const int lane = t & 63;
    const int wid  = t >> 6;
    const int wr   = wid >> 1, wc = wid & 1;
    const int l15  = lane & 15, l4 = lane >> 4;
    float sreg[4][4][4];
    #pragma unroll
    for (int am = 0; am < 4; ++am)
        #pragma unroll
        for (int r = 0; r < 4; ++r) {
            const long gi    = (long)(i0 + wr * 64 + am * 16 + l4 * 4 + r);
            const long basep = gi * NN + j0 + wc * 64 + l15;
            #pragma unroll
            for (int bn = 0; bn < 4; ++bn)
                sreg[am][bn][r] = S[basep + bn * 16];
        }
    f32x4 acc[4][4] = {};
    #pragma unroll
    for (int kb = 0; kb < 4; ++kb) {
        bf16x8 afl[4], bgr[4];
        #pragma unroll
        for (int m = 0; m < 4; ++m) {
            const int ia = wr * 64 + m * 16 + l15;
            afl[m] = *(const bf16x8*)(lds[0] + ia * 256 + (((kb * 4 + l4) ^ l15) << 4));
            const int jbq = wc * 64 + m * 16 + l15;
            bgr[m] = *(const bf16x8*)(lds[1] + jbq * 256 + (((kb * 4 + l4) ^ l15) << 4));
        }
        #pragma unroll
        for (int m = 0; m < 4; ++m)
            #pragma unroll
            for (int n = 0; n < 4; ++n)
                acc[m][n] = __builtin_amdgcn_mfma_f32_16x16x32_bf16(afl[m], bgr[n], acc[m][n], 0, 0, 0);
    }
    float lsum = 0.f;
    #pragma unroll
    for (int m = 0; m < 4; ++m)
        #pragma unroll
        for (int n = 0; n < 4; ++n)
            #pragma unroll
            for (int r = 0; r < 4; ++r) {
                const float o = 0.5f * acc[m][n][r];
                lsum += fmaf(-sreg[m][n][r], o, __logf(1.0f + o + eps));
            }
    float v = lsum;
    #pragma unroll
    for (int off = 32; off; off >>= 1) v += __shfl_down(v, off);
    if ((t & 63) == 0) red[t >> 6] = v;
    __syncthreads();
    if (t == 0) {
        const float tot = red[0] + red[1] + red[2] + red[3];
        atomicAdd(accum, (double)tot);   // slot 0
    }
}

// ---------------- small kernels ----------------
__global__ __launch_bounds__(256)
void bqc_kernel(const float* __restrict__ FP, const float* __restrict__ FM,
                const float* __restrict__ B, double* __restrict__ ws)
{
    __shared__ float red1[4], red2[4];
    const int n4 = DD * NN / 4;
    float s1 = 0.f, s2 = 0.f;
    for (int i = blockIdx.x * blockDim.x + threadIdx.x; i < n4;
         i += gridDim.x * blockDim.x) {
        const float4 p = ((const float4*)FP)[i];
        const float4 m = ((const float4*)FM)[i];
        const float4 b = ((const float4*)B)[i];
        float d;
        d = p.x - b.x; s1 += d * d;  d = p.y - b.y; s1 += d * d;
        d = p.z - b.z; s1 += d * d;  d = p.w - b.w; s1 += d * d;
        d = m.x - b.x; s2 += d * d;  d = m.y - b.y; s2 += d * d;
        d = m.z - b.z; s2 += d * d;  d = m.w - b.w; s2 += d * d;
    }
    const int t = threadIdx.x;
    #pragma unroll
    for (int off = 32; off; off >>= 1) {
        s1 += __shfl_down(s1, off);
        s2 += __shfl_down(s2, off);
    }
    if ((t & 63) == 0) { red1[t >> 6] = s1; red2[t >> 6] = s2; }
    __syncthreads();
    if (t == 0) {
        atomicAdd(&ws[128], (double)(red1[0] + red1[1] + red1[2] + red1[3]));
        atomicAdd(&ws[129], (double)(red2[0] + red2[1] + red2[2] + red2[3]));
    }
}

__global__ __launch_bounds__(256)
void fdc_kernel(const float* __restrict__ FP, const float* __restrict__ FM,
                double* __restrict__ ws)
{
    __shared__ float red[4];
    const float* F = (blockIdx.x >= DD) ? FM : FP;
    const int row = blockIdx.x & (DD - 1);
    float s = 0.f;
    const float4* rowp = (const float4*)&F[(long)row * NN];
    for (int i = threadIdx.x; i < NN / 4; i += blockDim.x) {
        const float4 v = rowp[i];
        s += v.x + v.y + v.z + v.w;
    }
    const int t = threadIdx.x;
    #pragma unroll
    for (int off = 32; off; off >>= 1) s += __shfl_down(s, off);
    if ((t & 63) == 0) red[t >> 6] = s;
    __syncthreads();
    if (t == 0) {
        const double rs = (double)(red[0] + red[1] + red[2] + red[3]);
        atomicAdd(&ws[130], rs * rs);
    }
}

__global__ void finalize_kernel(const double* __restrict__ ws, float* __restrict__ out)
{
    if (threadIdx.x == 0 && blockIdx.x == 0) {
        double s = 0.0;
        #pragma unroll
        for (int k = 0; k < 16; ++k) s += ws[k * 8];
        out[0] = (float)(s + ws[130] + sqrt(ws[128]) + sqrt(ws[129]));
    }
}

extern "C" void kernel_launch(void* const* d_in, const int* in_sizes, int n_in,
                              void* d_out, int out_size, void* d_ws, size_t ws_size,
                              hipStream_t stream)
{
    const float* SU = (const float*)d_in[0];
    const float* SP = (const float*)d_in[1];
    const float* SM = (const float*)d_in[2];
    const float* FP = (const float*)d_in[3];
    const float* FM = (const float*)d_in[4];
    const float* B  = (const float*)d_in[5];
    float*  out = (float*)d_out;
    double* ws  = (double*)d_ws;

    hipMemsetAsync(d_ws, 0, 4096, stream);

    const size_t fb   = (size_t)NN * DD * sizeof(__hip_bfloat16);   // 1 MB
    const size_t need = 4096 + 2 * fb;

    if (ws_size >= need) {
        char* base = (char*)d_ws + 4096;
        __hip_bfloat16* FPt = (__hip_bfloat16*)(base);
        __hip_bfloat16* FMt = (__hip_bfloat16*)(base + fb);
        convert_bqc_kernel<<<dim3(NN / 128, 2), 256, 0, stream>>>(FP, FM, B, FPt, FMt, ws);
        gemm_loss_sweep<<<768, 256, 0, stream>>>(SU, SP, SM, FPt, FMt, ws);
        fdc_kernel<<<256, 256, 0, stream>>>(FP, FM, ws);
    } else {
        dim3 grid(NN / 128, NN / 128);
        gemm_loss_mfma<<<grid, 256, 0, stream>>>(SU, FP, FM, 0.0f, ws);
        gemm_loss_mfma<<<grid, 256, 0, stream>>>(SP, FP, FP, 1e-8f, ws);
        gemm_loss_mfma<<<grid, 256, 0, stream>>>(SM, FM, FM, 1e-8f, ws);
        bqc_kernel<<<512, 256, 0, stream>>>(FP, FM, B, ws);
        fdc_kernel<<<256, 256, 0, stream>>>(FP, FM, ws);
    }
    finalize_kernel<<<1, 64, 0, stream>>>(ws, out);
}